// Round 1
// baseline (580.480 us; speedup 1.0000x reference)
//
#include <hip/hip_runtime.h>
#include <math.h>

#define NE 22   // electrons
#define NA 11   // atoms
#define HD 8    // HID
#define H2 16   // 2*HID
#define QN 22   // QNUM
#define NL 6    // layers

struct QCS { float c[QN]; float s[QN]; };

__device__ __forceinline__ float block_reduce_sum(float v, float* red, int tid) {
  red[tid] = v;
  __syncthreads();
  for (int off = 128; off > 0; off >>= 1) {
    if (tid < off) red[tid] += red[tid + off];
    __syncthreads();
  }
  float s = red[0];
  __syncthreads();
  return s;
}

__device__ __forceinline__ void ln_vec(const float* x, int n, const float* g,
                                       const float* bb, float* o) {
  float m = 0.f;
  for (int i = 0; i < n; i++) m += x[i];
  m /= (float)n;
  float v = 0.f;
  for (int i = 0; i < n; i++) { float d = x[i] - m; v += d * d; }
  v /= (float)n;
  float is = 1.0f / sqrtf(v + 1e-5f);
  for (int i = 0; i < n; i++) o[i] = (x[i] - m) * is * g[i] + bb[i];
}

__global__ __launch_bounds__(256) void small_net_kernel(
    const float* __restrict__ pos_a, const int* __restrict__ ix_a,
    const int* __restrict__ pos_ix, const int* __restrict__ atom_ix,
    const float* __restrict__ rpos_w, const float* __restrict__ emb_w,
    const float* __restrict__ emb_b,
    const float* __restrict__ Wq, const float* __restrict__ bq,
    const float* __restrict__ Wk, const float* __restrict__ bk,
    const float* __restrict__ Wv, const float* __restrict__ bv,
    const float* __restrict__ Wo, const float* __restrict__ bo,
    const float* __restrict__ W1, const float* __restrict__ b1,
    const float* __restrict__ W2, const float* __restrict__ b2,
    const float* __restrict__ ln1_g, const float* __restrict__ ln1_b,
    const float* __restrict__ ln2_g, const float* __restrict__ ln2_b,
    const float* __restrict__ Wi, const float* __restrict__ bi,
    const float* __restrict__ ni_g, const float* __restrict__ ni_b,
    const float* __restrict__ conv_a_w, const float* __restrict__ conv_e_w,
    float* __restrict__ xf_out)
{
  const int tid = threadIdx.x;
  const int b = tid / NA;
  const int a = tid % NA;
  const bool act = (tid < NE * NA);

  __shared__ float s_pos_e[NE][3];
  __shared__ float s_amp[NA];
  __shared__ float s_seq[NE][NA][HD];
  __shared__ float s_x[NE][NA][HD];
  __shared__ float s_er[NE][NA];
  __shared__ float s_red[256];
  __shared__ float s_scal[8];   // 0: amp_ae, 1: bias_ae, 4: amp_r2
  __shared__ float s_aeinv[HD];
  __shared__ union {
    struct { float q[NE][NA][HD]; float k[NE][NA][HD]; float v[NE][NA][HD]; } att;
    struct { float A[NE * H2 * NA]; float B[NE * H2 * 6]; } conv;
  } u;
  __shared__ float s_y[NE][H2];
  __shared__ float s_ampr[NE];
  __shared__ float s_eA[H2 * NE];
  __shared__ float s_eB[H2 * NA];
  __shared__ float s_y2[H2];

  // ---- embeddings ----
  if (tid < NE) {
    int p = pos_ix[tid], am = atom_ix[tid];
    for (int j = 0; j < 3; j++) s_pos_e[tid][j] = rpos_w[p * 3 + j] + pos_a[am * 3 + j];
  }
  if (tid < NA) s_amp[tid] = (float)ix_a[tid];
  __syncthreads();

  float rae = 0.f;
  if (act) {
    float d0 = s_pos_e[b][0] - pos_a[a * 3 + 0];
    float d1 = s_pos_e[b][1] - pos_a[a * 3 + 1];
    float d2 = s_pos_e[b][2] - pos_a[a * 3 + 2];
    rae = sqrtf(d0 * d0 + d1 * d1 + d2 * d2);
    float in4[4] = { d0, d1, d2, rae };
    for (int h = 0; h < HD; h++) {
      float s = emb_b[h];
      for (int j = 0; j < 4; j++) s += in4[j] * emb_w[h * 4 + j];
      s_seq[b][a][h] = s;
    }
  }
  // amp_ae = std(r_ae, ddof=1), bias_ae = mean(r_ae)   (two-pass)
  {
    float sum = block_reduce_sum(act ? rae : 0.f, s_red, tid);
    float mean = sum / (float)(NE * NA);
    float d = act ? (rae - mean) : 0.f;
    float ss = block_reduce_sum(d * d, s_red, tid);
    if (tid == 0) { s_scal[0] = sqrtf(ss / (float)(NE * NA - 1)); s_scal[1] = mean; }
  }
  __syncthreads();

  // ---- transformer layers ----
  const float iscale = 1.0f / sqrtf((float)HD);
  for (int l = 0; l < NL; l++) {
    if (act) {
      float xv[HD];
      float amp = s_amp[a];
      for (int h = 0; h < HD; h++) { xv[h] = amp * s_seq[b][a][h]; s_x[b][a][h] = xv[h]; }
      for (int h = 0; h < HD; h++) {
        float qq = bq[l * HD + h], kk = bk[l * HD + h], vv = bv[l * HD + h];
        const float* wq = Wq + (size_t)(l * HD + h) * HD;
        const float* wk = Wk + (size_t)(l * HD + h) * HD;
        const float* wv = Wv + (size_t)(l * HD + h) * HD;
        for (int h2 = 0; h2 < HD; h2++) {
          qq += xv[h2] * wq[h2];
          kk += xv[h2] * wk[h2];
          vv += xv[h2] * wv[h2];
        }
        u.att.q[b][a][h] = qq; u.att.k[b][a][h] = kk; u.att.v[b][a][h] = vv;
      }
    }
    __syncthreads();
    if (act) {
      float sc[NA];
      float mx = -1e30f;
      for (int ka = 0; ka < NA; ka++) {
        float s = 0.f;
        for (int h = 0; h < HD; h++) s += u.att.q[b][a][h] * u.att.k[b][ka][h];
        s *= iscale;
        sc[ka] = s;
        mx = fmaxf(mx, s);
      }
      float den = 0.f;
      for (int ka = 0; ka < NA; ka++) { sc[ka] = expf(sc[ka] - mx); den += sc[ka]; }
      float inv_den = 1.0f / den;
      float av[HD];
      for (int h = 0; h < HD; h++) av[h] = 0.f;
      for (int ka = 0; ka < NA; ka++)
        for (int h = 0; h < HD; h++) av[h] += sc[ka] * u.att.v[b][ka][h];
      for (int h = 0; h < HD; h++) av[h] *= inv_den;
      float xr[HD], xn[HD];
      for (int h = 0; h < HD; h++) {
        float t = bo[l * HD + h];
        const float* wo = Wo + (size_t)(l * HD + h) * HD;
        for (int h2 = 0; h2 < HD; h2++) t += av[h2] * wo[h2];
        xr[h] = s_x[b][a][h] + t;
      }
      ln_vec(xr, HD, ln1_g + l * HD, ln1_b + l * HD, xn);
      float f2[HD];
      for (int h = 0; h < HD; h++) f2[h] = b2[l * HD + h];
      for (int o = 0; o < 4 * HD; o++) {
        float t = b1[l * 4 * HD + o];
        const float* w1 = W1 + (size_t)(l * 4 * HD + o) * HD;
        for (int h = 0; h < HD; h++) t += xn[h] * w1[h];
        t = fmaxf(t, 0.f);
        for (int h = 0; h < HD; h++) f2[h] += t * W2[(size_t)(l * HD + h) * (4 * HD) + o];
      }
      for (int h = 0; h < HD; h++) xr[h] = xn[h] + f2[h];
      ln_vec(xr, HD, ln2_g + l * HD, ln2_b + l * HD, xn);
      for (int h = 0; h < HD; h++) s_seq[b][a][h] = xn[h];
    }
    __syncthreads();
  }

  // ---- ae_inv last row: inv(emb_w.T @ emb_w) @ emb_w.T, row 3 ----
  if (tid == 0) {
    double M[4][8];
    for (int i = 0; i < 4; i++)
      for (int j = 0; j < 4; j++) {
        double s = 0.0;
        for (int h = 0; h < HD; h++) s += (double)emb_w[h * 4 + i] * (double)emb_w[h * 4 + j];
        M[i][j] = s;
        M[i][4 + j] = (i == j) ? 1.0 : 0.0;
      }
    for (int c = 0; c < 4; c++) {
      int piv = c;
      for (int r2 = c + 1; r2 < 4; r2++) if (fabs(M[r2][c]) > fabs(M[piv][c])) piv = r2;
      if (piv != c) for (int j = 0; j < 8; j++) { double t = M[c][j]; M[c][j] = M[piv][j]; M[piv][j] = t; }
      double dd = M[c][c];
      for (int j = 0; j < 8; j++) M[c][j] /= dd;
      for (int r2 = 0; r2 < 4; r2++) if (r2 != c) {
        double f = M[r2][c];
        for (int j = 0; j < 8; j++) M[r2][j] -= f * M[c][j];
      }
    }
    for (int h = 0; h < HD; h++) {
      double s = 0.0;
      for (int j = 0; j < 4; j++) s += M[3][4 + j] * (double)emb_w[h * 4 + j];
      s_aeinv[h] = (float)s;
    }
  }
  __syncthreads();

  // ---- r projection + normalization + exp(-r) ----
  float rv = 0.f;
  if (act) for (int h = 0; h < HD; h++) rv += s_aeinv[h] * s_seq[b][a][h];
  {
    float sum = block_reduce_sum(act ? rv : 0.f, s_red, tid);
    float rm = sum / (float)(NE * NA);
    float d = act ? (rv - rm) : 0.f;
    float ss = block_reduce_sum(d * d, s_red, tid);
    float rs = sqrtf(ss / (float)(NE * NA - 1));
    if (act) {
      float rr = s_scal[0] * (rv - rm) / rs + s_scal[1];
      s_er[b][a] = expf(-rr);
    }
  }
  __syncthreads();

  // ---- Wi projection, transposed into conv buffer [b][o][a] ----
  if (act) {
    float e2 = s_er[b][a] * s_amp[a];
    float tv[HD];
    for (int h = 0; h < HD; h++) tv[h] = e2 * s_seq[b][a][h];
    for (int o = 0; o < H2; o++) {
      float s = bi[o];
      for (int h = 0; h < HD; h++) s += tv[h] * Wi[o * HD + h];
      u.conv.A[(b * H2 + o) * NA + a] = s;
    }
  }
  __syncthreads();

  // ---- y (mean over atoms), amp_r ----
  for (int idx = tid; idx < NE * H2; idx += 256) {
    int bb = idx / H2, o = idx % H2;
    float s = 0.f;
    for (int a2 = 0; a2 < NA; a2++) s += u.conv.A[(bb * H2 + o) * NA + a2];
    s_y[bb][o] = s / (float)NA;
  }
  if (tid < NE) {
    float s = 0.f;
    for (int a2 = 0; a2 < NA; a2++) s += s_er[tid][a2];
    s_ampr[tid] = s / (float)NA;
  }
  __syncthreads();

  // ---- atom conv pyramid: 11 -> 6 -> 3 -> 2 -> 1 -> 1 -> 1 (6 iters) ----
  float* pin = u.conv.A;
  float* pout = u.conv.B;
  int L = NA;
  for (int it = 0; it < 6; it++) {
    int Lo = (L - 1) / 2 + 1;
    int total = NE * H2 * Lo;
    for (int idx = tid; idx < total; idx += 256) {
      int bb = idx / (H2 * Lo);
      int rem = idx - bb * (H2 * Lo);
      int o = rem / Lo;
      int j = rem - o * Lo;
      const float* base = pin + bb * H2 * L;
      float acc = 0.f;
      for (int i = 0; i < H2; i++) {
        float x0 = base[i * L + 2 * j];
        float x1 = (2 * j + 1 < L) ? base[i * L + 2 * j + 1] : 0.f;
        acc += x0 * conv_a_w[(o * H2 + i) * 2 + 0] + x1 * conv_a_w[(o * H2 + i) * 2 + 1];
      }
      pout[(bb * H2 + o) * Lo + j] = acc;
    }
    __syncthreads();
    float* t = pin; pin = pout; pout = t;
    L = Lo;
  }

  // ---- per-electron LN, amp_r scaling, transpose to [o][b] ----
  if (tid < NE) {
    float t[H2], oo[H2];
    for (int o = 0; o < H2; o++) t[o] = s_y[tid][o] + pin[tid * H2 + o];
    ln_vec(t, H2, ni_g, ni_b, oo);
    float ar = s_ampr[tid];
    for (int o = 0; o < H2; o++) s_eA[o * NE + tid] = ar * oo[o];
  }
  __syncthreads();
  if (tid < H2) {
    float s = 0.f;
    for (int bb = 0; bb < NE; bb++) s += s_eA[tid * NE + bb];
    s_y2[tid] = s / (float)NE;
  }
  if (tid == 0) {
    float s = 0.f;
    for (int bb = 0; bb < NE; bb++) s += s_ampr[bb];
    s_scal[4] = s / (float)NE;   // amp_r2
  }
  __syncthreads();

  // ---- electron conv pyramid: 22 -> 11 -> 6 -> 3 -> 2 -> 1 x7 (11 iters) ----
  pin = s_eA; pout = s_eB;
  L = NE;
  for (int it = 0; it < 11; it++) {
    int Lo = (L - 1) / 2 + 1;
    int total = H2 * Lo;
    for (int idx = tid; idx < total; idx += 256) {
      int o = idx / Lo;
      int j = idx - o * Lo;
      float acc = 0.f;
      for (int i = 0; i < H2; i++) {
        float x0 = pin[i * L + 2 * j];
        float x1 = (2 * j + 1 < L) ? pin[i * L + 2 * j + 1] : 0.f;
        acc += x0 * conv_e_w[(o * H2 + i) * 2 + 0] + x1 * conv_e_w[(o * H2 + i) * 2 + 1];
      }
      pout[o * Lo + j] = acc;
    }
    __syncthreads();
    float* t = pin; pin = pout; pout = t;
    L = Lo;
  }

  // ---- final LN + amp_r2 scale -> xf[16] ----
  if (tid == 0) {
    float t[H2], oo[H2];
    for (int o = 0; o < H2; o++) t[o] = s_y2[o] + pin[o];
    ln_vec(t, H2, ni_g, ni_b, oo);
    float a2 = s_scal[4];
    for (int o = 0; o < H2; o++) xf_out[o] = a2 * oo[o];
  }
}

// ---- big memory-bound output projection: psi + 2^(Q/2) * bos ----
__global__ __launch_bounds__(256) void psi_kernel(
    const float* __restrict__ Wout, const float* __restrict__ bout,
    const float* __restrict__ xf, float* __restrict__ out, QCS cs, int n)
{
  __shared__ float s_xf[H2];
  if (threadIdx.x < H2) s_xf[threadIdx.x] = xf[threadIdx.x];
  __syncthreads();
  int i = blockIdx.x * blockDim.x + threadIdx.x;
  if (i >= n) return;
  const float4* w4 = reinterpret_cast<const float4*>(Wout + (size_t)i * H2);
  float4 w0 = w4[0], w1 = w4[1], w2 = w4[2], w3 = w4[3];
  float acc = bout[i];
  acc += w0.x * s_xf[0]  + w0.y * s_xf[1]  + w0.z * s_xf[2]  + w0.w * s_xf[3];
  acc += w1.x * s_xf[4]  + w1.y * s_xf[5]  + w1.z * s_xf[6]  + w1.w * s_xf[7];
  acc += w2.x * s_xf[8]  + w2.y * s_xf[9]  + w2.z * s_xf[10] + w2.w * s_xf[11];
  acc += w3.x * s_xf[12] + w3.y * s_xf[13] + w3.z * s_xf[14] + w3.w * s_xf[15];
  unsigned int ii = (unsigned int)i;
  float p = (float)(1 << (QN / 2));   // 2^(QNUM/2) = 2048
  #pragma unroll
  for (int q = 0; q < QN; q++) {
    p *= ((ii >> (QN - 1 - q)) & 1u) ? cs.s[q] : cs.c[q];
  }
  out[i] = acc + p;
}

extern "C" void kernel_launch(void* const* d_in, const int* in_sizes, int n_in,
                              void* d_out, int out_size, void* d_ws, size_t ws_size,
                              hipStream_t stream) {
  const float* pos_a   = (const float*)d_in[0];
  const int*   ix_a    = (const int*)d_in[1];
  const int*   pos_ix  = (const int*)d_in[2];
  const int*   atom_ix = (const int*)d_in[3];
  const float* rpos_w  = (const float*)d_in[4];
  const float* emb_w   = (const float*)d_in[5];
  const float* emb_b   = (const float*)d_in[6];
  const float* Wq = (const float*)d_in[7];   const float* bq = (const float*)d_in[8];
  const float* Wk = (const float*)d_in[9];   const float* bk = (const float*)d_in[10];
  const float* Wv = (const float*)d_in[11];  const float* bv = (const float*)d_in[12];
  const float* Wo = (const float*)d_in[13];  const float* bo = (const float*)d_in[14];
  const float* W1 = (const float*)d_in[15];  const float* b1 = (const float*)d_in[16];
  const float* W2 = (const float*)d_in[17];  const float* b2 = (const float*)d_in[18];
  const float* ln1_g = (const float*)d_in[19]; const float* ln1_b = (const float*)d_in[20];
  const float* ln2_g = (const float*)d_in[21]; const float* ln2_b = (const float*)d_in[22];
  const float* Wi = (const float*)d_in[23];  const float* bi = (const float*)d_in[24];
  const float* ni_g = (const float*)d_in[25]; const float* ni_b = (const float*)d_in[26];
  const float* conv_a_w = (const float*)d_in[27];
  const float* conv_e_w = (const float*)d_in[28];
  const float* Wout = (const float*)d_in[29];
  const float* bout = (const float*)d_in[30];
  float* xf = (float*)d_ws;

  small_net_kernel<<<1, 256, 0, stream>>>(pos_a, ix_a, pos_ix, atom_ix, rpos_w,
      emb_w, emb_b, Wq, bq, Wk, bk, Wv, bv, Wo, bo, W1, b1, W2, b2,
      ln1_g, ln1_b, ln2_g, ln2_b, Wi, bi, ni_g, ni_b, conv_a_w, conv_e_w, xf);

  // hf = [pi, 0] * (n_e/2) + [0] * (QNUM - n_e); per-qubit cos/sin of hf/2
  QCS cs;
  int n_e = in_sizes[2];
  for (int q = 0; q < QN; q++) {
    float hf = (q < n_e && (q % 2 == 0)) ? (float)M_PI : 0.0f;
    cs.c[q] = cosf(0.5f * hf);
    cs.s[q] = sinf(0.5f * hf);
  }

  int n = out_size;
  int blocks = (n + 255) / 256;
  psi_kernel<<<blocks, 256, 0, stream>>>(Wout, bout, xf, (float*)d_out, cs, n);
}

// Round 2
// 501.450 us; speedup vs baseline: 1.1576x; 1.1576x over previous
//
#include <hip/hip_runtime.h>
#include <math.h>

#define NE 22   // electrons
#define NA 11   // atoms
#define HD 8    // HID
#define H2 16   // 2*HID
#define QN 22   // QNUM
#define NL 6    // layers

struct QCS { float c[QN]; float s[QN]; };

__device__ __forceinline__ float block_reduce_sum(float v, float* red, int tid) {
  red[tid] = v;
  __syncthreads();
  for (int off = 128; off > 0; off >>= 1) {
    if (tid < off) red[tid] += red[tid + off];
    __syncthreads();
  }
  float s = red[0];
  __syncthreads();
  return s;
}

__device__ __forceinline__ void ln_vec(const float* x, int n, const float* g,
                                       const float* bb, float* o) {
  float m = 0.f;
  for (int i = 0; i < n; i++) m += x[i];
  m /= (float)n;
  float v = 0.f;
  for (int i = 0; i < n; i++) { float d = x[i] - m; v += d * d; }
  v /= (float)n;
  float is = 1.0f / sqrtf(v + 1e-5f);
  for (int i = 0; i < n; i++) o[i] = (x[i] - m) * is * g[i] + bb[i];
}

// coalesced float4 global->LDS copy; n4 = number of float4 elements
__device__ __forceinline__ void cp4(float* __restrict__ dst,
                                    const float* __restrict__ src,
                                    int n4, int tid) {
  const float4* s = (const float4*)src;
  float4* d = (float4*)dst;
  for (int i = tid; i < n4; i += 256) d[i] = s[i];
}

__global__ __launch_bounds__(256) void small_net_kernel(
    const float* __restrict__ pos_a, const int* __restrict__ ix_a,
    const int* __restrict__ pos_ix, const int* __restrict__ atom_ix,
    const float* __restrict__ rpos_w, const float* __restrict__ emb_w,
    const float* __restrict__ emb_b,
    const float* __restrict__ Wq, const float* __restrict__ bq,
    const float* __restrict__ Wk, const float* __restrict__ bk,
    const float* __restrict__ Wv, const float* __restrict__ bv,
    const float* __restrict__ Wo, const float* __restrict__ bo,
    const float* __restrict__ W1, const float* __restrict__ b1,
    const float* __restrict__ W2, const float* __restrict__ b2,
    const float* __restrict__ ln1_g, const float* __restrict__ ln1_b,
    const float* __restrict__ ln2_g, const float* __restrict__ ln2_b,
    const float* __restrict__ Wi, const float* __restrict__ bi,
    const float* __restrict__ ni_g, const float* __restrict__ ni_b,
    const float* __restrict__ conv_a_w, const float* __restrict__ conv_e_w,
    float* __restrict__ xf_out)
{
  const int tid = threadIdx.x;
  const int b = tid / NA;
  const int a = tid % NA;
  const bool act = (tid < NE * NA);

  __shared__ float s_pos_e[NE][3];
  __shared__ float s_amp[NA];
  __shared__ float s_seq[NE][NA][HD];
  __shared__ float s_x[NE][NA][HD];
  __shared__ float s_er[NE][NA];
  __shared__ float s_red[256];
  __shared__ float s_scal[8];   // 0: amp_ae, 1: bias_ae, 4: amp_r2
  __shared__ float s_aeinv[HD];
  __shared__ union {
    struct { float q[NE][NA][HD]; float k[NE][NA][HD]; float v[NE][NA][HD]; } att;
    struct { float A[NE * H2 * NA]; float B[NE * H2 * 6]; } conv;
  } u;
  __shared__ float s_y[NE][H2];
  __shared__ float s_ampr[NE];
  __shared__ float s_eA[H2 * NE];
  __shared__ float s_eB[H2 * NA];
  __shared__ float s_y2[H2];

  // ---- LDS-staged weights (all inner-loop reads come from here) ----
  __shared__ float w_q[NL * HD * HD], w_k[NL * HD * HD], w_v[NL * HD * HD], w_o[NL * HD * HD];
  __shared__ float c_bq[NL * HD], c_bk[NL * HD], c_bv[NL * HD], c_bo[NL * HD];
  __shared__ float w_1[NL * 4 * HD * HD], c_b1[NL * 4 * HD];
  __shared__ float w_2[NL * HD * 4 * HD], c_b2[NL * HD];
  __shared__ float c_l1g[NL * HD], c_l1b[NL * HD], c_l2g[NL * HD], c_l2b[NL * HD];
  __shared__ float w_i[H2 * HD], c_bi[H2], c_nig[H2], c_nib[H2];
  __shared__ float c_caw[H2 * H2 * 2], c_cew[H2 * H2 * 2];
  __shared__ float c_ew[HD * 4], c_eb[HD];

  cp4(w_q, Wq, NL * HD * HD / 4, tid);
  cp4(w_k, Wk, NL * HD * HD / 4, tid);
  cp4(w_v, Wv, NL * HD * HD / 4, tid);
  cp4(w_o, Wo, NL * HD * HD / 4, tid);
  cp4(c_bq, bq, NL * HD / 4, tid);
  cp4(c_bk, bk, NL * HD / 4, tid);
  cp4(c_bv, bv, NL * HD / 4, tid);
  cp4(c_bo, bo, NL * HD / 4, tid);
  cp4(w_1, W1, NL * 4 * HD * HD / 4, tid);
  cp4(c_b1, b1, NL * 4 * HD / 4, tid);
  cp4(w_2, W2, NL * HD * 4 * HD / 4, tid);
  cp4(c_b2, b2, NL * HD / 4, tid);
  cp4(c_l1g, ln1_g, NL * HD / 4, tid);
  cp4(c_l1b, ln1_b, NL * HD / 4, tid);
  cp4(c_l2g, ln2_g, NL * HD / 4, tid);
  cp4(c_l2b, ln2_b, NL * HD / 4, tid);
  cp4(w_i, Wi, H2 * HD / 4, tid);
  cp4(c_bi, bi, H2 / 4, tid);
  cp4(c_nig, ni_g, H2 / 4, tid);
  cp4(c_nib, ni_b, H2 / 4, tid);
  cp4(c_caw, conv_a_w, H2 * H2 * 2 / 4, tid);
  cp4(c_cew, conv_e_w, H2 * H2 * 2 / 4, tid);
  cp4(c_ew, emb_w, HD * 4 / 4, tid);
  cp4(c_eb, emb_b, HD / 4, tid);

  // ---- small scattered inputs ----
  if (tid < NE) {
    int p = pos_ix[tid], am = atom_ix[tid];
    for (int j = 0; j < 3; j++) s_pos_e[tid][j] = rpos_w[p * 3 + j] + pos_a[am * 3 + j];
  }
  if (tid < NA) s_amp[tid] = (float)ix_a[tid];
  __syncthreads();

  float rae = 0.f;
  if (act) {
    float d0 = s_pos_e[b][0] - pos_a[a * 3 + 0];
    float d1 = s_pos_e[b][1] - pos_a[a * 3 + 1];
    float d2 = s_pos_e[b][2] - pos_a[a * 3 + 2];
    rae = sqrtf(d0 * d0 + d1 * d1 + d2 * d2);
    float in4[4] = { d0, d1, d2, rae };
    #pragma unroll
    for (int h = 0; h < HD; h++) {
      float s = c_eb[h];
      #pragma unroll
      for (int j = 0; j < 4; j++) s += in4[j] * c_ew[h * 4 + j];
      s_seq[b][a][h] = s;
    }
  }
  // amp_ae = std(r_ae, ddof=1), bias_ae = mean(r_ae)   (two-pass)
  {
    float sum = block_reduce_sum(act ? rae : 0.f, s_red, tid);
    float mean = sum / (float)(NE * NA);
    float d = act ? (rae - mean) : 0.f;
    float ss = block_reduce_sum(d * d, s_red, tid);
    if (tid == 0) { s_scal[0] = sqrtf(ss / (float)(NE * NA - 1)); s_scal[1] = mean; }
  }
  __syncthreads();

  // ---- transformer layers (all weights from LDS) ----
  const float iscale = 1.0f / sqrtf((float)HD);
  for (int l = 0; l < NL; l++) {
    if (act) {
      float xv[HD];
      float amp = s_amp[a];
      #pragma unroll
      for (int h = 0; h < HD; h++) { xv[h] = amp * s_seq[b][a][h]; s_x[b][a][h] = xv[h]; }
      #pragma unroll
      for (int h = 0; h < HD; h++) {
        float qq = c_bq[l * HD + h], kk = c_bk[l * HD + h], vv = c_bv[l * HD + h];
        const float* wq = w_q + (l * HD + h) * HD;
        const float* wk = w_k + (l * HD + h) * HD;
        const float* wv = w_v + (l * HD + h) * HD;
        #pragma unroll
        for (int h2 = 0; h2 < HD; h2++) {
          qq += xv[h2] * wq[h2];
          kk += xv[h2] * wk[h2];
          vv += xv[h2] * wv[h2];
        }
        u.att.q[b][a][h] = qq; u.att.k[b][a][h] = kk; u.att.v[b][a][h] = vv;
      }
    }
    __syncthreads();
    if (act) {
      float sc[NA];
      float mx = -1e30f;
      #pragma unroll
      for (int ka = 0; ka < NA; ka++) {
        float s = 0.f;
        #pragma unroll
        for (int h = 0; h < HD; h++) s += u.att.q[b][a][h] * u.att.k[b][ka][h];
        s *= iscale;
        sc[ka] = s;
        mx = fmaxf(mx, s);
      }
      float den = 0.f;
      #pragma unroll
      for (int ka = 0; ka < NA; ka++) { sc[ka] = expf(sc[ka] - mx); den += sc[ka]; }
      float inv_den = 1.0f / den;
      float av[HD];
      #pragma unroll
      for (int h = 0; h < HD; h++) av[h] = 0.f;
      #pragma unroll
      for (int ka = 0; ka < NA; ka++)
        #pragma unroll
        for (int h = 0; h < HD; h++) av[h] += sc[ka] * u.att.v[b][ka][h];
      #pragma unroll
      for (int h = 0; h < HD; h++) av[h] *= inv_den;
      float xr[HD], xn[HD];
      #pragma unroll
      for (int h = 0; h < HD; h++) {
        float t = c_bo[l * HD + h];
        const float* wo = w_o + (l * HD + h) * HD;
        #pragma unroll
        for (int h2 = 0; h2 < HD; h2++) t += av[h2] * wo[h2];
        xr[h] = s_x[b][a][h] + t;
      }
      ln_vec(xr, HD, c_l1g + l * HD, c_l1b + l * HD, xn);
      float f2[HD];
      #pragma unroll
      for (int h = 0; h < HD; h++) f2[h] = c_b2[l * HD + h];
      #pragma unroll 4
      for (int o = 0; o < 4 * HD; o++) {
        float t = c_b1[l * 4 * HD + o];
        const float* w1 = w_1 + (l * 4 * HD + o) * HD;
        #pragma unroll
        for (int h = 0; h < HD; h++) t += xn[h] * w1[h];
        t = fmaxf(t, 0.f);
        #pragma unroll
        for (int h = 0; h < HD; h++) f2[h] += t * w_2[(l * HD + h) * (4 * HD) + o];
      }
      #pragma unroll
      for (int h = 0; h < HD; h++) xr[h] = xn[h] + f2[h];
      ln_vec(xr, HD, c_l2g + l * HD, c_l2b + l * HD, xn);
      #pragma unroll
      for (int h = 0; h < HD; h++) s_seq[b][a][h] = xn[h];
    }
    __syncthreads();
  }

  // ---- ae_inv last row: inv(emb_w.T @ emb_w) @ emb_w.T, row 3 ----
  if (tid == 0) {
    double M[4][8];
    for (int i = 0; i < 4; i++)
      for (int j = 0; j < 4; j++) {
        double s = 0.0;
        for (int h = 0; h < HD; h++) s += (double)c_ew[h * 4 + i] * (double)c_ew[h * 4 + j];
        M[i][j] = s;
        M[i][4 + j] = (i == j) ? 1.0 : 0.0;
      }
    for (int c = 0; c < 4; c++) {
      int piv = c;
      for (int r2 = c + 1; r2 < 4; r2++) if (fabs(M[r2][c]) > fabs(M[piv][c])) piv = r2;
      if (piv != c) for (int j = 0; j < 8; j++) { double t = M[c][j]; M[c][j] = M[piv][j]; M[piv][j] = t; }
      double dd = M[c][c];
      for (int j = 0; j < 8; j++) M[c][j] /= dd;
      for (int r2 = 0; r2 < 4; r2++) if (r2 != c) {
        double f = M[r2][c];
        for (int j = 0; j < 8; j++) M[r2][j] -= f * M[c][j];
      }
    }
    for (int h = 0; h < HD; h++) {
      double s = 0.0;
      for (int j = 0; j < 4; j++) s += M[3][4 + j] * (double)c_ew[h * 4 + j];
      s_aeinv[h] = (float)s;
    }
  }
  __syncthreads();

  // ---- r projection + normalization + exp(-r) ----
  float rv = 0.f;
  if (act) {
    #pragma unroll
    for (int h = 0; h < HD; h++) rv += s_aeinv[h] * s_seq[b][a][h];
  }
  {
    float sum = block_reduce_sum(act ? rv : 0.f, s_red, tid);
    float rm = sum / (float)(NE * NA);
    float d = act ? (rv - rm) : 0.f;
    float ss = block_reduce_sum(d * d, s_red, tid);
    float rs = sqrtf(ss / (float)(NE * NA - 1));
    if (act) {
      float rr = s_scal[0] * (rv - rm) / rs + s_scal[1];
      s_er[b][a] = expf(-rr);
    }
  }
  __syncthreads();

  // ---- Wi projection, transposed into conv buffer [b][o][a] ----
  if (act) {
    float e2 = s_er[b][a] * s_amp[a];
    float tv[HD];
    #pragma unroll
    for (int h = 0; h < HD; h++) tv[h] = e2 * s_seq[b][a][h];
    #pragma unroll
    for (int o = 0; o < H2; o++) {
      float s = c_bi[o];
      #pragma unroll
      for (int h = 0; h < HD; h++) s += tv[h] * w_i[o * HD + h];
      u.conv.A[(b * H2 + o) * NA + a] = s;
    }
  }
  __syncthreads();

  // ---- y (mean over atoms), amp_r ----
  for (int idx = tid; idx < NE * H2; idx += 256) {
    int bb = idx / H2, o = idx % H2;
    float s = 0.f;
    for (int a2 = 0; a2 < NA; a2++) s += u.conv.A[(bb * H2 + o) * NA + a2];
    s_y[bb][o] = s / (float)NA;
  }
  if (tid < NE) {
    float s = 0.f;
    for (int a2 = 0; a2 < NA; a2++) s += s_er[tid][a2];
    s_ampr[tid] = s / (float)NA;
  }
  __syncthreads();

  // ---- atom conv pyramid: 11 -> 6 -> 3 -> 2 -> 1 -> 1 -> 1 (6 iters) ----
  float* pin = u.conv.A;
  float* pout = u.conv.B;
  int L = NA;
  for (int it = 0; it < 6; it++) {
    int Lo = (L - 1) / 2 + 1;
    int total = NE * H2 * Lo;
    for (int idx = tid; idx < total; idx += 256) {
      int bb = idx / (H2 * Lo);
      int rem = idx - bb * (H2 * Lo);
      int o = rem / Lo;
      int j = rem - o * Lo;
      const float* base = pin + bb * H2 * L;
      float acc = 0.f;
      #pragma unroll
      for (int i = 0; i < H2; i++) {
        float x0 = base[i * L + 2 * j];
        float x1 = (2 * j + 1 < L) ? base[i * L + 2 * j + 1] : 0.f;
        acc += x0 * c_caw[(o * H2 + i) * 2 + 0] + x1 * c_caw[(o * H2 + i) * 2 + 1];
      }
      pout[(bb * H2 + o) * Lo + j] = acc;
    }
    __syncthreads();
    float* t = pin; pin = pout; pout = t;
    L = Lo;
  }

  // ---- per-electron LN, amp_r scaling, transpose to [o][b] ----
  if (tid < NE) {
    float t[H2], oo[H2];
    #pragma unroll
    for (int o = 0; o < H2; o++) t[o] = s_y[tid][o] + pin[tid * H2 + o];
    ln_vec(t, H2, c_nig, c_nib, oo);
    float ar = s_ampr[tid];
    #pragma unroll
    for (int o = 0; o < H2; o++) s_eA[o * NE + tid] = ar * oo[o];
  }
  __syncthreads();
  if (tid < H2) {
    float s = 0.f;
    for (int bb = 0; bb < NE; bb++) s += s_eA[tid * NE + bb];
    s_y2[tid] = s / (float)NE;
  }
  if (tid == 0) {
    float s = 0.f;
    for (int bb = 0; bb < NE; bb++) s += s_ampr[bb];
    s_scal[4] = s / (float)NE;   // amp_r2
  }
  __syncthreads();

  // ---- electron conv pyramid: 22 -> 11 -> 6 -> 3 -> 2 -> 1 x7 (11 iters) ----
  pin = s_eA; pout = s_eB;
  L = NE;
  for (int it = 0; it < 11; it++) {
    int Lo = (L - 1) / 2 + 1;
    int total = H2 * Lo;
    for (int idx = tid; idx < total; idx += 256) {
      int o = idx / Lo;
      int j = idx - o * Lo;
      float acc = 0.f;
      #pragma unroll
      for (int i = 0; i < H2; i++) {
        float x0 = pin[i * L + 2 * j];
        float x1 = (2 * j + 1 < L) ? pin[i * L + 2 * j + 1] : 0.f;
        acc += x0 * c_cew[(o * H2 + i) * 2 + 0] + x1 * c_cew[(o * H2 + i) * 2 + 1];
      }
      pout[o * Lo + j] = acc;
    }
    __syncthreads();
    float* t = pin; pin = pout; pout = t;
    L = Lo;
  }

  // ---- final LN + amp_r2 scale -> xf[16] ----
  if (tid == 0) {
    float t[H2], oo[H2];
    for (int o = 0; o < H2; o++) t[o] = s_y2[o] + pin[o];
    ln_vec(t, H2, c_nig, c_nib, oo);
    float a2 = s_scal[4];
    for (int o = 0; o < H2; o++) xf_out[o] = a2 * oo[o];
  }
}

// ---- big memory-bound output projection: psi + 2^(Q/2) * bos ----
__global__ __launch_bounds__(256) void psi_kernel(
    const float* __restrict__ Wout, const float* __restrict__ bout,
    const float* __restrict__ xf, float* __restrict__ out, QCS cs, int n)
{
  __shared__ float s_xf[H2];
  if (threadIdx.x < H2) s_xf[threadIdx.x] = xf[threadIdx.x];
  __syncthreads();
  int i = blockIdx.x * blockDim.x + threadIdx.x;
  if (i >= n) return;
  const float4* w4 = reinterpret_cast<const float4*>(Wout + (size_t)i * H2);
  float4 w0 = w4[0], w1 = w4[1], w2 = w4[2], w3 = w4[3];
  float acc = bout[i];
  acc += w0.x * s_xf[0]  + w0.y * s_xf[1]  + w0.z * s_xf[2]  + w0.w * s_xf[3];
  acc += w1.x * s_xf[4]  + w1.y * s_xf[5]  + w1.z * s_xf[6]  + w1.w * s_xf[7];
  acc += w2.x * s_xf[8]  + w2.y * s_xf[9]  + w2.z * s_xf[10] + w2.w * s_xf[11];
  acc += w3.x * s_xf[12] + w3.y * s_xf[13] + w3.z * s_xf[14] + w3.w * s_xf[15];
  unsigned int ii = (unsigned int)i;
  float p = (float)(1 << (QN / 2));   // 2^(QNUM/2) = 2048
  #pragma unroll
  for (int q = 0; q < QN; q++) {
    p *= ((ii >> (QN - 1 - q)) & 1u) ? cs.s[q] : cs.c[q];
  }
  out[i] = acc + p;
}

extern "C" void kernel_launch(void* const* d_in, const int* in_sizes, int n_in,
                              void* d_out, int out_size, void* d_ws, size_t ws_size,
                              hipStream_t stream) {
  const float* pos_a   = (const float*)d_in[0];
  const int*   ix_a    = (const int*)d_in[1];
  const int*   pos_ix  = (const int*)d_in[2];
  const int*   atom_ix = (const int*)d_in[3];
  const float* rpos_w  = (const float*)d_in[4];
  const float* emb_w   = (const float*)d_in[5];
  const float* emb_b   = (const float*)d_in[6];
  const float* Wq = (const float*)d_in[7];   const float* bq = (const float*)d_in[8];
  const float* Wk = (const float*)d_in[9];   const float* bk = (const float*)d_in[10];
  const float* Wv = (const float*)d_in[11];  const float* bv = (const float*)d_in[12];
  const float* Wo = (const float*)d_in[13];  const float* bo = (const float*)d_in[14];
  const float* W1 = (const float*)d_in[15];  const float* b1 = (const float*)d_in[16];
  const float* W2 = (const float*)d_in[17];  const float* b2 = (const float*)d_in[18];
  const float* ln1_g = (const float*)d_in[19]; const float* ln1_b = (const float*)d_in[20];
  const float* ln2_g = (const float*)d_in[21]; const float* ln2_b = (const float*)d_in[22];
  const float* Wi = (const float*)d_in[23];  const float* bi = (const float*)d_in[24];
  const float* ni_g = (const float*)d_in[25]; const float* ni_b = (const float*)d_in[26];
  const float* conv_a_w = (const float*)d_in[27];
  const float* conv_e_w = (const float*)d_in[28];
  const float* Wout = (const float*)d_in[29];
  const float* bout = (const float*)d_in[30];
  float* xf = (float*)d_ws;

  small_net_kernel<<<1, 256, 0, stream>>>(pos_a, ix_a, pos_ix, atom_ix, rpos_w,
      emb_w, emb_b, Wq, bq, Wk, bk, Wv, bv, Wo, bo, W1, b1, W2, b2,
      ln1_g, ln1_b, ln2_g, ln2_b, Wi, bi, ni_g, ni_b, conv_a_w, conv_e_w, xf);

  // hf = [pi, 0] * (n_e/2) + [0] * (QNUM - n_e); per-qubit cos/sin of hf/2
  QCS cs;
  int n_e = in_sizes[2];
  for (int q = 0; q < QN; q++) {
    float hf = (q < n_e && (q % 2 == 0)) ? (float)M_PI : 0.0f;
    cs.c[q] = cosf(0.5f * hf);
    cs.s[q] = sinf(0.5f * hf);
  }

  int n = out_size;
  int blocks = (n + 255) / 256;
  psi_kernel<<<blocks, 256, 0, stream>>>(Wout, bout, xf, (float*)d_out, cs, n);
}